// Round 1
// baseline (7382.671 us; speedup 1.0000x reference)
//
#include <hip/hip_runtime.h>
#include <hip/hip_bf16.h>

#define BATCH 256
#define SEQ   250
#define HID   512
#define INDIM 5

#define NBLK  256
#define MB    32   // batch rows per block (8 batch tiles)
#define HB    16   // hidden units per block (32 hidden tiles)

typedef __attribute__((ext_vector_type(8))) short short8;
typedef __attribute__((ext_vector_type(4))) float f32x4;

__device__ __forceinline__ float sigmoidf_fast(float x) {
  return 1.0f / (1.0f + __expf(-x));
}
__device__ __forceinline__ float tanhf_fast(float x) {
  return 2.0f / (1.0f + __expf(-2.0f * x)) - 1.0f;
}
__device__ __forceinline__ unsigned short f2bf_rne(float x) {
  union { float f; unsigned u; } v; v.f = x;
  unsigned r = v.u + 0x7fffu + ((v.u >> 16) & 1u);
  return (unsigned short)(r >> 16);
}

// Persistent LSTM: 256 blocks (one per CU-ish), weight-stationary W_hh in
// registers as MFMA B-fragments, grid barrier per timestep via d_ws flags.
__global__ __launch_bounds__(256, 2) void lstm_persist(
    const float* __restrict__ strokes, const float* __restrict__ W_ih,
    const float* __restrict__ W_hh, const float* __restrict__ b_ih,
    const float* __restrict__ b_hh, const float* __restrict__ W_out,
    const float* __restrict__ b_out, float* __restrict__ out,
    unsigned short* __restrict__ hbuf,   // 2 * 256 * 512 bf16 (double buffer)
    float* __restrict__ hfinal,          // 256 * 512 f32
    int* __restrict__ arrive)            // 256 ints (poisoned 0xAAAAAAAA = negative)
{
  const int tid  = threadIdx.x;
  const int bid  = blockIdx.x;
  const int bt   = bid & 7;      // batch tile (bid%8 -> same-bt blocks share XCD for h L2 locality)
  const int ht   = bid >> 3;     // hidden tile 0..31
  const int wv   = tid >> 6;     // wave id = gate type 0..3 (i,f,g,o)
  const int lane = tid & 63;
  const int n16  = lane & 15;
  const int q    = lane >> 4;

  __shared__ float g_lds[4][MB][17];        // gate values, padded
  __shared__ float wih_lds[4][HB][INDIM];
  __shared__ float bias_lds[4][HB];

  // ---- preload W_ih slice + combined biases into LDS
  if (tid < 64) {
    int g = tid >> 4, j = tid & 15;
    int r = g * HID + ht * HB + j;
    #pragma unroll
    for (int i = 0; i < INDIM; ++i) wih_lds[g][j][i] = W_ih[r * INDIM + i];
    bias_lds[g][j] = b_ih[r] + b_hh[r];
  }

  // ---- preload W_hh as bf16 MFMA B-fragments (weight-stationary)
  // wave wv holds gate rows r = wv*512 + ht*16 + n16, B[k][n]: k = kb*32+q*8+j
  short8 wfrag[16];
  {
    const float* wr = W_hh + (size_t)(wv * HID + ht * HB + n16) * HID;
    #pragma unroll
    for (int kb = 0; kb < 16; ++kb) {
      const float* p = wr + kb * 32 + q * 8;
      short8 f;
      #pragma unroll
      for (int j = 0; j < 8; ++j) f[j] = (short)f2bf_rne(p[j]);
      wfrag[kb] = f;
    }
  }
  __syncthreads();

  // activation-phase mapping: thread -> (batch row am, hidden pair aj)
  const int am = tid >> 3;            // 0..31
  const int aj = (tid & 7) * 2;       // 0,2,..,14
  const int ab = bt * MB + am;        // global batch row
  float c0 = 0.f, c1 = 0.f;

  unsigned short* hb0 = hbuf;
  unsigned short* hb1 = hbuf + BATCH * HID;

  for (int t = 0; t < SEQ; ++t) {
    unsigned short* hprev = (t & 1) ? hb0 : hb1;
    unsigned short* hcur  = (t & 1) ? hb1 : hb0;

    f32x4 acc[2][2] = {};  // [mtile][k-parity] -> 4 chains for MFMA latency
    if (t > 0) {
      #pragma unroll
      for (int kb = 0; kb < 16; ++kb) {
        #pragma unroll
        for (int mt = 0; mt < 2; ++mt) {
          const short8 a = *reinterpret_cast<const short8*>(
              hprev + (size_t)(bt * MB + mt * 16 + n16) * HID + kb * 32 + q * 8);
          acc[mt][kb & 1] = __builtin_amdgcn_mfma_f32_16x16x32_bf16(
              a, wfrag[kb], acc[mt][kb & 1], 0, 0, 0);
        }
      }
    }

    // C-layout: col = lane&15, row = q*4 + reg
    #pragma unroll
    for (int mt = 0; mt < 2; ++mt) {
      #pragma unroll
      for (int r = 0; r < 4; ++r) {
        g_lds[wv][mt * 16 + q * 4 + r][n16] = acc[mt][0][r] + acc[mt][1][r];
      }
    }
    __syncthreads();

    // activations: 2 hidden cells per thread, x-projection on the fly
    const float* sp = strokes + ((size_t)ab * SEQ + t) * INDIM;
    float s0 = sp[0], s1 = sp[1], s2 = sp[2], s3 = sp[3], s4 = sp[4];

    float hv[2];
    #pragma unroll
    for (int e = 0; e < 2; ++e) {
      int j = aj + e;
      float pre[4];
      #pragma unroll
      for (int g = 0; g < 4; ++g) {
        pre[g] = bias_lds[g][j] + g_lds[g][am][j]
               + s0 * wih_lds[g][j][0] + s1 * wih_lds[g][j][1]
               + s2 * wih_lds[g][j][2] + s3 * wih_lds[g][j][3]
               + s4 * wih_lds[g][j][4];
      }
      float ig = sigmoidf_fast(pre[0]);
      float fg = sigmoidf_fast(pre[1]);
      float gg = tanhf_fast(pre[2]);
      float og = sigmoidf_fast(pre[3]);
      float& c = e ? c1 : c0;
      c = fg * c + ig * gg;
      hv[e] = og * tanhf_fast(c);
    }
    unsigned pack = (unsigned)f2bf_rne(hv[0]) | ((unsigned)f2bf_rne(hv[1]) << 16);
    *reinterpret_cast<unsigned*>(hcur + (size_t)ab * HID + ht * HB + aj) = pack;
    if (t == SEQ - 1) {
      hfinal[(size_t)ab * HID + ht * HB + aj]     = hv[0];
      hfinal[(size_t)ab * HID + ht * HB + aj + 1] = hv[1];
    }

    // ---- grid barrier, generation t+1 (monotone; 0xAAAAAAAA poison is negative)
    __syncthreads();                       // drains block's stores (vmcnt 0)
    if (tid == 0) {
      __threadfence();                     // agent release: L2 writeback
      __hip_atomic_store(&arrive[bid], t + 1, __ATOMIC_RELAXED,
                         __HIP_MEMORY_SCOPE_AGENT);
    }
    while (__hip_atomic_load(&arrive[tid], __ATOMIC_RELAXED,
                             __HIP_MEMORY_SCOPE_AGENT) < t + 1) { }
    __threadfence();                       // agent acquire: invalidate caches
    __syncthreads();
  }

  // final projection + leaky_relu + sigmoid, one block
  if (bid == 0) {
    const int b = tid;
    const float* hr = hfinal + (size_t)b * HID;
    float s = 0.f;
    for (int k = 0; k < HID; ++k) s += hr[k] * W_out[k];
    float raw = s + b_out[0];
    float lr = raw > 0.f ? raw : 0.1f * raw;
    out[b] = 1.0f / (1.0f + __expf(-lr));
  }
}

extern "C" void kernel_launch(void* const* d_in, const int* in_sizes, int n_in,
                              void* d_out, int out_size, void* d_ws, size_t ws_size,
                              hipStream_t stream) {
  const float* strokes = (const float*)d_in[0];
  const float* W_ih    = (const float*)d_in[1];
  const float* W_hh    = (const float*)d_in[2];
  const float* b_ih    = (const float*)d_in[3];
  const float* b_hh    = (const float*)d_in[4];
  const float* W_out   = (const float*)d_in[5];
  const float* b_out   = (const float*)d_in[6];
  float* out = (float*)d_out;

  char* ws = (char*)d_ws;
  unsigned short* hbuf = (unsigned short*)ws;                       // 512 KB
  float* hfinal = (float*)(ws + (size_t)2 * BATCH * HID * 2);       // 512 KB
  int* arrive   = (int*)(ws + (size_t)2 * BATCH * HID * 2
                            + (size_t)BATCH * HID * 4);             // 1 KB

  lstm_persist<<<NBLK, 256, 0, stream>>>(strokes, W_ih, W_hh, b_ih, b_hh,
                                         W_out, b_out, out, hbuf, hfinal, arrive);
}

// Round 2
// 6399.451 us; speedup vs baseline: 1.1536x; 1.1536x over previous
//
#include <hip/hip_runtime.h>
#include <hip/hip_bf16.h>

#define BATCH 256
#define SEQ   250
#define HID   512
#define INDIM 5

#define NBLK  256
#define MB    32   // batch rows per block (8 batch tiles = 8 barrier groups)
#define HB    16   // hidden units per block (32 hidden tiles = 32 group members)

typedef __attribute__((ext_vector_type(8))) short short8;
typedef __attribute__((ext_vector_type(4))) float f32x4;

__device__ __forceinline__ float sigmoidf_fast(float x) {
  return 1.0f / (1.0f + __expf(-x));
}
__device__ __forceinline__ float tanhf_fast(float x) {
  return 2.0f / (1.0f + __expf(-2.0f * x)) - 1.0f;
}
__device__ __forceinline__ unsigned short f2bf_rne(float x) {
  union { float f; unsigned u; } v; v.f = x;
  unsigned r = v.u + 0x7fffu + ((v.u >> 16) & 1u);
  return (unsigned short)(r >> 16);
}

// Persistent LSTM. Barrier is per batch-tile group (32 blocks), with
// per-member generation flags padded to one 64B line each, and only 32
// pollers per block (tid<32, one flag each). R1's all-thread poll of a
// 1KB flag array was MALL-contention-bound at ~29us/step.
__global__ __launch_bounds__(256, 2) void lstm_persist(
    const float* __restrict__ strokes, const float* __restrict__ W_ih,
    const float* __restrict__ W_hh, const float* __restrict__ b_ih,
    const float* __restrict__ b_hh, const float* __restrict__ W_out,
    const float* __restrict__ b_out, float* __restrict__ out,
    unsigned short* __restrict__ hbuf,   // 2 * 256 * 512 bf16 (double buffer)
    float* __restrict__ hfinal,          // 256 * 512 f32
    int* __restrict__ flags)             // 256 * 16 ints (64B spacing; poison 0xAA.. < 0)
{
  const int tid  = threadIdx.x;
  const int bid  = blockIdx.x;
  const int bt   = bid & 7;      // batch tile / barrier group
  const int ht   = bid >> 3;     // hidden tile 0..31 / group member
  const int wv   = tid >> 6;     // wave id = gate type 0..3 (i,f,g,o)
  const int lane = tid & 63;
  const int n16  = lane & 15;
  const int q    = lane >> 4;

  __shared__ float g_lds[4][MB][17];        // gate values, padded
  __shared__ float wih_lds[4][HB][INDIM];
  __shared__ float bias_lds[4][HB];

  // ---- preload W_ih slice + combined biases into LDS
  if (tid < 64) {
    int g = tid >> 4, j = tid & 15;
    int r = g * HID + ht * HB + j;
    #pragma unroll
    for (int i = 0; i < INDIM; ++i) wih_lds[g][j][i] = W_ih[r * INDIM + i];
    bias_lds[g][j] = b_ih[r] + b_hh[r];
  }

  // ---- preload W_hh as bf16 MFMA B-fragments (weight-stationary)
  short8 wfrag[16];
  {
    const float* wr = W_hh + (size_t)(wv * HID + ht * HB + n16) * HID;
    #pragma unroll
    for (int kb = 0; kb < 16; ++kb) {
      const float* p = wr + kb * 32 + q * 8;
      short8 f;
      #pragma unroll
      for (int j = 0; j < 8; ++j) f[j] = (short)f2bf_rne(p[j]);
      wfrag[kb] = f;
    }
  }
  __syncthreads();

  // activation-phase mapping: thread -> (batch row am, hidden pair aj)
  const int am = tid >> 3;            // 0..31
  const int aj = (tid & 7) * 2;       // 0,2,..,14
  const int ab = bt * MB + am;        // global batch row
  float c0 = 0.f, c1 = 0.f;

  unsigned short* hb0 = hbuf;
  unsigned short* hb1 = hbuf + BATCH * HID;

  for (int t = 0; t < SEQ; ++t) {
    unsigned short* hprev = (t & 1) ? hb0 : hb1;
    unsigned short* hcur  = (t & 1) ? hb1 : hb0;

    f32x4 acc[2][2] = {};  // [mtile][k-parity]
    if (t > 0) {
      #pragma unroll
      for (int kb = 0; kb < 16; ++kb) {
        #pragma unroll
        for (int mt = 0; mt < 2; ++mt) {
          const short8 a = *reinterpret_cast<const short8*>(
              hprev + (size_t)(bt * MB + mt * 16 + n16) * HID + kb * 32 + q * 8);
          acc[mt][kb & 1] = __builtin_amdgcn_mfma_f32_16x16x32_bf16(
              a, wfrag[kb], acc[mt][kb & 1], 0, 0, 0);
        }
      }
    }

    // C-layout: col = lane&15, row = q*4 + reg
    #pragma unroll
    for (int mt = 0; mt < 2; ++mt) {
      #pragma unroll
      for (int r = 0; r < 4; ++r) {
        g_lds[wv][mt * 16 + q * 4 + r][n16] = acc[mt][0][r] + acc[mt][1][r];
      }
    }
    __syncthreads();

    // activations: 2 hidden cells per thread, x-projection on the fly
    const float* sp = strokes + ((size_t)ab * SEQ + t) * INDIM;
    float s0 = sp[0], s1 = sp[1], s2 = sp[2], s3 = sp[3], s4 = sp[4];

    float hv[2];
    #pragma unroll
    for (int e = 0; e < 2; ++e) {
      int j = aj + e;
      float pre[4];
      #pragma unroll
      for (int g = 0; g < 4; ++g) {
        pre[g] = bias_lds[g][j] + g_lds[g][am][j]
               + s0 * wih_lds[g][j][0] + s1 * wih_lds[g][j][1]
               + s2 * wih_lds[g][j][2] + s3 * wih_lds[g][j][3]
               + s4 * wih_lds[g][j][4];
      }
      float ig = sigmoidf_fast(pre[0]);
      float fg = sigmoidf_fast(pre[1]);
      float gg = tanhf_fast(pre[2]);
      float og = sigmoidf_fast(pre[3]);
      float& c = e ? c1 : c0;
      c = fg * c + ig * gg;
      hv[e] = og * tanhf_fast(c);
    }
    unsigned pack = (unsigned)f2bf_rne(hv[0]) | ((unsigned)f2bf_rne(hv[1]) << 16);
    *reinterpret_cast<unsigned*>(hcur + (size_t)ab * HID + ht * HB + aj) = pack;
    if (t == SEQ - 1) {
      hfinal[(size_t)ab * HID + ht * HB + aj]     = hv[0];
      hfinal[(size_t)ab * HID + ht * HB + aj + 1] = hv[1];
    }

    // ---- group barrier (32 blocks sharing bt), generation t+1
    __syncthreads();                       // drains this block's h stores
    if (tid == 0) {
      __threadfence();                     // release: L2 writeback to MALL
      __hip_atomic_store(&flags[bid * 16], t + 1, __ATOMIC_RELAXED,
                         __HIP_MEMORY_SCOPE_AGENT);
    }
    if (tid < 32) {                        // poller j watches member (bt, j)
      while (__hip_atomic_load(&flags[(bt + 8 * tid) * 16], __ATOMIC_RELAXED,
                               __HIP_MEMORY_SCOPE_AGENT) < t + 1) { }
    }
    __syncthreads();
    __threadfence();                       // acquire: invalidate stale L1/L2
  }

  // final projection + leaky_relu + sigmoid: member ht==0 of each group
  // handles its own 32 batch rows (hfinal rows produced by this group).
  if (ht == 0 && tid < 32) {
    const int b = bt * MB + tid;
    const float* hr = hfinal + (size_t)b * HID;
    float s = 0.f;
    for (int k = 0; k < HID; ++k) s += hr[k] * W_out[k];
    float raw = s + b_out[0];
    float lr = raw > 0.f ? raw : 0.1f * raw;
    out[b] = 1.0f / (1.0f + __expf(-lr));
  }
}

extern "C" void kernel_launch(void* const* d_in, const int* in_sizes, int n_in,
                              void* d_out, int out_size, void* d_ws, size_t ws_size,
                              hipStream_t stream) {
  const float* strokes = (const float*)d_in[0];
  const float* W_ih    = (const float*)d_in[1];
  const float* W_hh    = (const float*)d_in[2];
  const float* b_ih    = (const float*)d_in[3];
  const float* b_hh    = (const float*)d_in[4];
  const float* W_out   = (const float*)d_in[5];
  const float* b_out   = (const float*)d_in[6];
  float* out = (float*)d_out;

  char* ws = (char*)d_ws;
  unsigned short* hbuf = (unsigned short*)ws;                       // 512 KB
  float* hfinal = (float*)(ws + (size_t)2 * BATCH * HID * 2);       // 512 KB
  int* flags    = (int*)(ws + (size_t)2 * BATCH * HID * 2
                            + (size_t)BATCH * HID * 4);             // 16 KB

  lstm_persist<<<NBLK, 256, 0, stream>>>(strokes, W_ih, W_hh, b_ih, b_hh,
                                         W_out, b_out, out, hbuf, hfinal, flags);
}

// Round 3
// 1328.484 us; speedup vs baseline: 5.5572x; 4.8171x over previous
//
#include <hip/hip_runtime.h>
#include <hip/hip_bf16.h>

#define BATCH 256
#define SEQ   250
#define HID   512
#define INDIM 5

#define NBLK  256
#define MB    32   // batch rows per block (8 batch tiles = 8 barrier groups)
#define HB    16   // hidden units per block (32 hidden tiles = 32 group members)
#define HPAD  8    // +16B pad per LDS h row
#define HSTRIDE (HID + HPAD)   // 520 bf16 = 1040 B (8B- and 16B-aligned rows)

typedef __attribute__((ext_vector_type(8))) short short8;
typedef __attribute__((ext_vector_type(4))) float f32x4;

__device__ __forceinline__ float sigmoidf_fast(float x) {
  return 1.0f / (1.0f + __expf(-x));
}
__device__ __forceinline__ float tanhf_fast(float x) {
  return 2.0f / (1.0f + __expf(-2.0f * x)) - 1.0f;
}
__device__ __forceinline__ unsigned short f2bf_rne(float x) {
  union { float f; unsigned u; } v; v.f = x;
  unsigned r = v.u + 0x7fffu + ((v.u >> 16) & 1u);
  return (unsigned short)(r >> 16);
}
__device__ __forceinline__ float bf2f(unsigned short h) {
  union { unsigned u; float f; } v; v.u = ((unsigned)h) << 16;
  return v.f;
}

// Persistent LSTM, FENCE-FREE cross-block exchange:
// - h written with device-scope relaxed atomic stores (write-through to MALL,
//   no dirty L2 lines anywhere)
// - h read with device-scope relaxed atomic 8B loads, staged once into LDS
//   (no buffer_inv needed: consumer loads bypass L1/L2 entirely)
// - per-group (32 blocks sharing a batch tile) generation barrier; release
//   is a single __ATOMIC_RELEASE flag store (wbl2 walks an empty dirty set).
// R1/R2 spent ~25us/step on __threadfence wbl2/inv storms (1280 L2
// walk ops per step); this removes all of them.
__global__ __launch_bounds__(256, 2) void lstm_persist(
    const float* __restrict__ strokes, const float* __restrict__ W_ih,
    const float* __restrict__ W_hh, const float* __restrict__ b_ih,
    const float* __restrict__ b_hh, const float* __restrict__ W_out,
    const float* __restrict__ b_out, float* __restrict__ out,
    unsigned short* __restrict__ hbuf,   // 2 * 256 * 512 bf16 (double buffer)
    int* __restrict__ flags)             // 256 * 16 ints (64B apart; poison < 0)
{
  const int tid  = threadIdx.x;
  const int bid  = blockIdx.x;
  const int bt   = bid & 7;      // batch tile / barrier group
  const int ht   = bid >> 3;     // hidden tile 0..31 / group member
  const int wv   = tid >> 6;     // wave id = gate type 0..3 (i,f,g,o)
  const int lane = tid & 63;
  const int n16  = lane & 15;
  const int q    = lane >> 4;

  __shared__ unsigned short h_lds[MB * HSTRIDE];  // 33280 B staged h tile
  __shared__ float g_lds[4][MB][17];              // gate values, padded
  __shared__ float wih_lds[4][HB][INDIM];
  __shared__ float bias_lds[4][HB];

  // ---- preload W_ih slice + combined biases into LDS
  if (tid < 64) {
    int g = tid >> 4, j = tid & 15;
    int r = g * HID + ht * HB + j;
    #pragma unroll
    for (int i = 0; i < INDIM; ++i) wih_lds[g][j][i] = W_ih[r * INDIM + i];
    bias_lds[g][j] = b_ih[r] + b_hh[r];
  }

  // ---- preload W_hh as bf16 MFMA B-fragments (weight-stationary)
  short8 wfrag[16];
  {
    const float* wr = W_hh + (size_t)(wv * HID + ht * HB + n16) * HID;
    #pragma unroll
    for (int kb = 0; kb < 16; ++kb) {
      const float* p = wr + kb * 32 + q * 8;
      short8 f;
      #pragma unroll
      for (int j = 0; j < 8; ++j) f[j] = (short)f2bf_rne(p[j]);
      wfrag[kb] = f;
    }
  }
  __syncthreads();

  // activation-phase mapping: thread -> (batch row am, hidden pair aj)
  const int am = tid >> 3;            // 0..31
  const int aj = (tid & 7) * 2;       // 0,2,..,14
  const int ab = bt * MB + am;        // global batch row
  float c0 = 0.f, c1 = 0.f;

  unsigned short* hb0 = hbuf;
  unsigned short* hb1 = hbuf + BATCH * HID;

  for (int t = 0; t < SEQ; ++t) {
    unsigned short* hprev = (t & 1) ? hb0 : hb1;
    unsigned short* hcur  = (t & 1) ? hb1 : hb0;

    f32x4 acc[2][2] = {};
    if (t > 0) {
      // ---- stage h(t-1) rows [bt*32, bt*32+32) x HID into LDS.
      // Device-scope loads (bypass L1/L2 -> MALL): contiguous 32KB region,
      // 256 threads x 16 x 8B, fully coalesced.
      const unsigned long long* hsrc = reinterpret_cast<const unsigned long long*>(
          hprev + (size_t)bt * MB * HID);
      unsigned long long tmp[16];
      #pragma unroll
      for (int i = 0; i < 16; ++i) {
        tmp[i] = __hip_atomic_load(hsrc + i * 256 + tid, __ATOMIC_RELAXED,
                                   __HIP_MEMORY_SCOPE_AGENT);
      }
      #pragma unroll
      for (int i = 0; i < 16; ++i) {
        int off  = i * 256 + tid;     // 8B-chunk index; 128 chunks per row
        int row  = off >> 7;
        int col4 = off & 127;         // 8B chunk within row
        *reinterpret_cast<unsigned long long*>(
            &h_lds[row * HSTRIDE + col4 * 4]) = tmp[i];
      }
      __syncthreads();

      #pragma unroll
      for (int kb = 0; kb < 16; ++kb) {
        #pragma unroll
        for (int mt = 0; mt < 2; ++mt) {
          const short8 a = *reinterpret_cast<const short8*>(
              &h_lds[(mt * 16 + n16) * HSTRIDE + kb * 32 + q * 8]);
          acc[mt][kb & 1] = __builtin_amdgcn_mfma_f32_16x16x32_bf16(
              a, wfrag[kb], acc[mt][kb & 1], 0, 0, 0);
        }
      }
    }

    // C-layout: col = lane&15, row = q*4 + reg
    #pragma unroll
    for (int mt = 0; mt < 2; ++mt) {
      #pragma unroll
      for (int r = 0; r < 4; ++r) {
        g_lds[wv][mt * 16 + q * 4 + r][n16] = acc[mt][0][r] + acc[mt][1][r];
      }
    }
    __syncthreads();

    // activations: 2 hidden cells per thread, x-projection on the fly
    const float* sp = strokes + ((size_t)ab * SEQ + t) * INDIM;
    float s0 = sp[0], s1 = sp[1], s2 = sp[2], s3 = sp[3], s4 = sp[4];

    float hv[2];
    #pragma unroll
    for (int e = 0; e < 2; ++e) {
      int j = aj + e;
      float pre[4];
      #pragma unroll
      for (int g = 0; g < 4; ++g) {
        pre[g] = bias_lds[g][j] + g_lds[g][am][j]
               + s0 * wih_lds[g][j][0] + s1 * wih_lds[g][j][1]
               + s2 * wih_lds[g][j][2] + s3 * wih_lds[g][j][3]
               + s4 * wih_lds[g][j][4];
      }
      float ig = sigmoidf_fast(pre[0]);
      float fg = sigmoidf_fast(pre[1]);
      float gg = tanhf_fast(pre[2]);
      float og = sigmoidf_fast(pre[3]);
      float& c = e ? c1 : c0;
      c = fg * c + ig * gg;
      hv[e] = og * tanhf_fast(c);
    }
    // h store: device-scope write-through (one u32 = 2 bf16 per thread)
    unsigned pack = (unsigned)f2bf_rne(hv[0]) | ((unsigned)f2bf_rne(hv[1]) << 16);
    __hip_atomic_store(
        reinterpret_cast<unsigned*>(hcur + (size_t)ab * HID + ht * HB + aj),
        pack, __ATOMIC_RELAXED, __HIP_MEMORY_SCOPE_AGENT);

    // ---- group barrier (32 blocks sharing bt), generation t+1
    __syncthreads();   // drains all waves' h stores (vmcnt 0 at s_barrier)
    if (tid == 0) {
      __hip_atomic_store(&flags[bid * 16], t + 1, __ATOMIC_RELEASE,
                         __HIP_MEMORY_SCOPE_AGENT);
    }
    if (tid < 32) {    // poller j watches member (bt, j), one 64B line each
      while (__hip_atomic_load(&flags[(bt + 8 * tid) * 16], __ATOMIC_RELAXED,
                               __HIP_MEMORY_SCOPE_AGENT) < t + 1) { }
    }
    __syncthreads();
  }

  // ---- final projection: member ht==0 of each group handles its 32 rows.
  // h(249) lives in hb1 (t=249 odd); last barrier made it MALL-visible.
  if (ht == 0) {
    const unsigned long long* hsrc = reinterpret_cast<const unsigned long long*>(
        hb1 + (size_t)bt * MB * HID);
    unsigned long long tmp[16];
    #pragma unroll
    for (int i = 0; i < 16; ++i) {
      tmp[i] = __hip_atomic_load(hsrc + i * 256 + tid, __ATOMIC_RELAXED,
                                 __HIP_MEMORY_SCOPE_AGENT);
    }
    #pragma unroll
    for (int i = 0; i < 16; ++i) {
      int off  = i * 256 + tid;
      int row  = off >> 7;
      int col4 = off & 127;
      *reinterpret_cast<unsigned long long*>(
          &h_lds[row * HSTRIDE + col4 * 4]) = tmp[i];
    }
    __syncthreads();
    if (tid < 32) {
      const int b = bt * MB + tid;
      float s = 0.f;
      for (int k = 0; k < HID; ++k)
        s += bf2f(h_lds[tid * HSTRIDE + k]) * W_out[k];
      float raw = s + b_out[0];
      float lr = raw > 0.f ? raw : 0.1f * raw;
      out[b] = 1.0f / (1.0f + __expf(-lr));
    }
  }
}

extern "C" void kernel_launch(void* const* d_in, const int* in_sizes, int n_in,
                              void* d_out, int out_size, void* d_ws, size_t ws_size,
                              hipStream_t stream) {
  const float* strokes = (const float*)d_in[0];
  const float* W_ih    = (const float*)d_in[1];
  const float* W_hh    = (const float*)d_in[2];
  const float* b_ih    = (const float*)d_in[3];
  const float* b_hh    = (const float*)d_in[4];
  const float* W_out   = (const float*)d_in[5];
  const float* b_out   = (const float*)d_in[6];
  float* out = (float*)d_out;

  char* ws = (char*)d_ws;
  unsigned short* hbuf = (unsigned short*)ws;                        // 512 KB
  int* flags = (int*)(ws + (size_t)2 * BATCH * HID * 2);             // 16 KB

  lstm_persist<<<NBLK, 256, 0, stream>>>(strokes, W_ih, W_hh, b_ih, b_hh,
                                         W_out, b_out, out, hbuf, flags);
}

// Round 4
// 1281.775 us; speedup vs baseline: 5.7597x; 1.0364x over previous
//
#include <hip/hip_runtime.h>
#include <hip/hip_bf16.h>

#define BATCH 256
#define SEQ   250
#define HID   512
#define INDIM 5

#define NBLK  256
#define MB    32   // batch rows per block (8 batch tiles = 8 barrier groups)
#define HB    16   // hidden units per block (32 hidden tiles = 32 group members)

typedef __attribute__((ext_vector_type(8))) short short8;
typedef __attribute__((ext_vector_type(4))) float f32x4;
typedef __attribute__((ext_vector_type(4))) unsigned int u32x4;

__device__ __forceinline__ float sigmoidf_fast(float x) {
  return 1.0f / (1.0f + __expf(-x));
}
__device__ __forceinline__ float tanhf_fast(float x) {
  return 2.0f / (1.0f + __expf(-2.0f * x)) - 1.0f;
}
__device__ __forceinline__ unsigned short f2bf_rne(float x) {
  union { float f; unsigned u; } v; v.f = x;
  unsigned r = v.u + 0x7fffu + ((v.u >> 16) & 1u);
  return (unsigned short)(r >> 16);
}
__device__ __forceinline__ float bf2f(unsigned short h) {
  union { unsigned u; float f; } v; v.u = ((unsigned)h) << 16;
  return v.f;
}

// Cache-bypassing (sc0 sc1 -> straight to MALL, same path as agent-scope
// relaxed atomics) 16B load, issued WITHOUT an implicit per-load waitcnt so
// 8 of them pipeline into one MALL round trip.
__device__ __forceinline__ void mall_load_16B(u32x4& dst, const void* ptr) {
  asm volatile("global_load_dwordx4 %0, %1, off sc0 sc1"
               : "=v"(dst) : "v"(ptr) : "memory");
}
__device__ __forceinline__ void vm_drain() {
  asm volatile("s_waitcnt vmcnt(0)" ::: "memory");
}

// Persistent LSTM, fence-free exchange (R3) + batched staging loads and
// XOR-swizzled LDS h-tile (R4).
// LDS h tile: 32 rows x 64 16B-chunks, physical chunk = c ^ (row & 7)
// -> conflict-free ds_read_b128 fragments AND conflict-free staging writes.
__global__ __launch_bounds__(256, 2) void lstm_persist(
    const float* __restrict__ strokes, const float* __restrict__ W_ih,
    const float* __restrict__ W_hh, const float* __restrict__ b_ih,
    const float* __restrict__ b_hh, const float* __restrict__ W_out,
    const float* __restrict__ b_out, float* __restrict__ out,
    unsigned short* __restrict__ hbuf,   // 2 * 256 * 512 bf16 (double buffer)
    int* __restrict__ flags)             // 256 * 16 ints (64B apart; poison < 0)
{
  const int tid  = threadIdx.x;
  const int bid  = blockIdx.x;
  const int bt   = bid & 7;      // batch tile / barrier group
  const int ht   = bid >> 3;     // hidden tile 0..31 / group member
  const int wv   = tid >> 6;     // wave id = gate type 0..3 (i,f,g,o)
  const int lane = tid & 63;
  const int n16  = lane & 15;
  const int q    = lane >> 4;

  __shared__ u32x4 h_lds[MB * 64];                // 32 KB, swizzled 16B chunks
  __shared__ float g_lds[4][MB][17];              // gate values, padded
  __shared__ float wih_lds[4][HB][INDIM];
  __shared__ float bias_lds[4][HB];

  // ---- preload W_ih slice + combined biases into LDS
  if (tid < 64) {
    int g = tid >> 4, j = tid & 15;
    int r = g * HID + ht * HB + j;
    #pragma unroll
    for (int i = 0; i < INDIM; ++i) wih_lds[g][j][i] = W_ih[r * INDIM + i];
    bias_lds[g][j] = b_ih[r] + b_hh[r];
  }

  // ---- preload W_hh as bf16 MFMA B-fragments (weight-stationary)
  short8 wfrag[16];
  {
    const float* wr = W_hh + (size_t)(wv * HID + ht * HB + n16) * HID;
    #pragma unroll
    for (int kb = 0; kb < 16; ++kb) {
      const float* p = wr + kb * 32 + q * 8;
      short8 f;
      #pragma unroll
      for (int j = 0; j < 8; ++j) f[j] = (short)f2bf_rne(p[j]);
      wfrag[kb] = f;
    }
  }
  __syncthreads();

  // activation-phase mapping: thread -> (batch row am, hidden pair aj)
  const int am = tid >> 3;            // 0..31
  const int aj = (tid & 7) * 2;       // 0,2,..,14
  const int ab = bt * MB + am;        // global batch row
  float c0 = 0.f, c1 = 0.f;

  unsigned short* hb0 = hbuf;
  unsigned short* hb1 = hbuf + BATCH * HID;

  // staging geometry: thread handles 16B chunks off = i*256+tid, i<8;
  // row = off>>6 (64 chunks/row), c = off&63, phys chunk = c ^ (row&7).
  const int s_row = tid >> 6;          // base row contribution from tid
  (void)s_row;

  for (int t = 0; t < SEQ; ++t) {
    unsigned short* hprev = (t & 1) ? hb0 : hb1;
    unsigned short* hcur  = (t & 1) ? hb1 : hb0;

    // strokes are read-only input: load before staging to overlap
    const float* sp = strokes + ((size_t)ab * SEQ + t) * INDIM;
    float s0 = sp[0], s1 = sp[1], s2 = sp[2], s3 = sp[3], s4 = sp[4];

    f32x4 acc[2][2] = {};
    if (t > 0) {
      // ---- stage h(t-1) tile (32 rows x 512 bf16 = 32 KB) into LDS.
      // 8 x 16B per thread, batched: ONE MALL round trip, not 8/16.
      const char* hsrc = reinterpret_cast<const char*>(hprev + (size_t)bt * MB * HID);
      u32x4 tmp[8];
      #pragma unroll
      for (int i = 0; i < 8; ++i) {
        mall_load_16B(tmp[i], hsrc + (size_t)(i * 256 + tid) * 16);
      }
      vm_drain();
      #pragma unroll
      for (int i = 0; i < 8; ++i) {
        int off = i * 256 + tid;
        int row = off >> 6;
        int c   = off & 63;
        h_lds[row * 64 + (c ^ (row & 7))] = tmp[i];
      }
      __syncthreads();

      #pragma unroll
      for (int kb = 0; kb < 16; ++kb) {
        #pragma unroll
        for (int mt = 0; mt < 2; ++mt) {
          const int row = mt * 16 + n16;
          const int c   = kb * 4 + q;                 // 16B chunk in row
          const short8 a = *reinterpret_cast<const short8*>(
              &h_lds[row * 64 + (c ^ (row & 7))]);
          acc[mt][kb & 1] = __builtin_amdgcn_mfma_f32_16x16x32_bf16(
              a, wfrag[kb], acc[mt][kb & 1], 0, 0, 0);
        }
      }
    }

    // C-layout: col = lane&15, row = q*4 + reg
    #pragma unroll
    for (int mt = 0; mt < 2; ++mt) {
      #pragma unroll
      for (int r = 0; r < 4; ++r) {
        g_lds[wv][mt * 16 + q * 4 + r][n16] = acc[mt][0][r] + acc[mt][1][r];
      }
    }
    __syncthreads();

    float hv[2];
    #pragma unroll
    for (int e = 0; e < 2; ++e) {
      int j = aj + e;
      float pre[4];
      #pragma unroll
      for (int g = 0; g < 4; ++g) {
        pre[g] = bias_lds[g][j] + g_lds[g][am][j]
               + s0 * wih_lds[g][j][0] + s1 * wih_lds[g][j][1]
               + s2 * wih_lds[g][j][2] + s3 * wih_lds[g][j][3]
               + s4 * wih_lds[g][j][4];
      }
      float ig = sigmoidf_fast(pre[0]);
      float fg = sigmoidf_fast(pre[1]);
      float gg = tanhf_fast(pre[2]);
      float og = sigmoidf_fast(pre[3]);
      float& c = e ? c1 : c0;
      c = fg * c + ig * gg;
      hv[e] = og * tanhf_fast(c);
    }
    // h store: device-scope write-through (one u32 = 2 bf16 per thread)
    unsigned pack = (unsigned)f2bf_rne(hv[0]) | ((unsigned)f2bf_rne(hv[1]) << 16);
    __hip_atomic_store(
        reinterpret_cast<unsigned*>(hcur + (size_t)ab * HID + ht * HB + aj),
        pack, __ATOMIC_RELAXED, __HIP_MEMORY_SCOPE_AGENT);

    // ---- group barrier (32 blocks sharing bt), generation t+1
    __syncthreads();   // all waves' h stores acked at MALL before flag
    if (tid == 0) {
      __hip_atomic_store(&flags[bid * 16], t + 1, __ATOMIC_RELEASE,
                         __HIP_MEMORY_SCOPE_AGENT);
    }
    if (tid < 32) {    // poller j watches member (bt, j), one 64B line each
      while (__hip_atomic_load(&flags[(bt + 8 * tid) * 16], __ATOMIC_RELAXED,
                               __HIP_MEMORY_SCOPE_AGENT) < t + 1) { }
    }
    __syncthreads();
  }

  // ---- final projection: member ht==0 of each group handles its 32 rows.
  // h(249) lives in hb1 (t=249 odd); last barrier made it MALL-visible.
  if (ht == 0) {
    const char* hsrc = reinterpret_cast<const char*>(hb1 + (size_t)bt * MB * HID);
    u32x4 tmp[8];
    #pragma unroll
    for (int i = 0; i < 8; ++i) {
      mall_load_16B(tmp[i], hsrc + (size_t)(i * 256 + tid) * 16);
    }
    vm_drain();
    #pragma unroll
    for (int i = 0; i < 8; ++i) {
      int off = i * 256 + tid;
      int row = off >> 6;
      int c   = off & 63;
      h_lds[row * 64 + (c ^ (row & 7))] = tmp[i];
    }
    __syncthreads();
    if (tid < 32) {
      const int b = bt * MB + tid;
      float s = 0.f;
      for (int k = 0; k < HID; ++k) {
        int c = k >> 3;   // 16B chunk
        const unsigned short* ch = reinterpret_cast<const unsigned short*>(
            &h_lds[tid * 64 + (c ^ (tid & 7))]);
        s += bf2f(ch[k & 7]) * W_out[k];
      }
      float raw = s + b_out[0];
      float lr = raw > 0.f ? raw : 0.1f * raw;
      out[b] = 1.0f / (1.0f + __expf(-lr));
    }
  }
}

extern "C" void kernel_launch(void* const* d_in, const int* in_sizes, int n_in,
                              void* d_out, int out_size, void* d_ws, size_t ws_size,
                              hipStream_t stream) {
  const float* strokes = (const float*)d_in[0];
  const float* W_ih    = (const float*)d_in[1];
  const float* W_hh    = (const float*)d_in[2];
  const float* b_ih    = (const float*)d_in[3];
  const float* b_hh    = (const float*)d_in[4];
  const float* W_out   = (const float*)d_in[5];
  const float* b_out   = (const float*)d_in[6];
  float* out = (float*)d_out;

  char* ws = (char*)d_ws;
  unsigned short* hbuf = (unsigned short*)ws;                        // 512 KB
  int* flags = (int*)(ws + (size_t)2 * BATCH * HID * 2);             // 16 KB

  lstm_persist<<<NBLK, 256, 0, stream>>>(strokes, W_ih, W_hh, b_ih, b_hh,
                                         W_out, b_out, out, hbuf, flags);
}